// Round 1
// baseline (654.064 us; speedup 1.0000x reference)
//
#include <hip/hip_runtime.h>

typedef __bf16 bf16x8 __attribute__((ext_vector_type(8)));
typedef float f32x16 __attribute__((ext_vector_type(16)));
typedef unsigned short ushort8 __attribute__((ext_vector_type(8)));

__device__ __forceinline__ unsigned short f2bf(float f) {
    unsigned int u = __float_as_uint(f);
    u += 0x7FFFu + ((u >> 16) & 1u);   // round-to-nearest-even
    return (unsigned short)(u >> 16);
}

// ===========================================================================
// NEW PATH (needs ~68.4 MB workspace)
// ws layout: [cbf 1 MB][csq 4 KB][xsq 256 KB][xbf 64 MB]
// xbf fragment layout per 64-row block rb:
//   xbf[rb*32768 + ((mt*32 + sl)*64 + kh*32 + n)*8 + j] = x[rb*64+mt*32+n][sl*16+kh*8+j]
// so a wave's A-fragment (mt, sl) is 64 lanes x 16 B contiguous -> global_load_lds-able.
// cbf layout identical to previous session (verified):
//   cbf[((T*32 + s)*64 + kh*32 + n)*8 + j] = cl[T*32+n][s*16+kh*8+j]
// ===========================================================================

__global__ __launch_bounds__(256) void prep_all(
    const float* __restrict__ x, const float* __restrict__ cl,
    unsigned short* __restrict__ xbf, unsigned short* __restrict__ cbf,
    float* __restrict__ csq, float* __restrict__ xsq) {
    const int bid = blockIdx.x;
    const int t   = threadIdx.x;
    if (bid < 4096) {
        // ---- x part: 1M threads, thread -> (row = gx>>4, 32-col chunk c = gx&15)
        const int gx  = bid * 256 + t;
        const int row = gx >> 4, c = gx & 15;
        const float4* xg = (const float4*)(x + ((size_t)row << 9) + c * 32);
        float4 v[8];
#pragma unroll
        for (int i = 0; i < 8; ++i) v[i] = xg[i];
        float ssq = 0.f;
#pragma unroll
        for (int i = 0; i < 8; ++i)
            ssq += v[i].x*v[i].x + v[i].y*v[i].y + v[i].z*v[i].z + v[i].w*v[i].w;
        // reduce ||x||^2 across the 16 lanes sharing a row (lane bits 0..3)
#pragma unroll
        for (int off = 1; off <= 8; off <<= 1) ssq += __shfl_xor(ssq, off);
        if ((t & 15) == 0) xsq[row] = ssq;

        const int rb = row >> 6, mt = (row >> 5) & 1, n = row & 31;
#pragma unroll
        for (int g = 0; g < 4; ++g) {
            const float4 a = v[2*g], b = v[2*g+1];
            ushort8 h;
            h[0]=f2bf(a.x); h[1]=f2bf(a.y); h[2]=f2bf(a.z); h[3]=f2bf(a.w);
            h[4]=f2bf(b.x); h[5]=f2bf(b.y); h[6]=f2bf(b.z); h[7]=f2bf(b.w);
            const int d0 = c * 32 + g * 8;
            const int sl = d0 >> 4, kh = (d0 >> 3) & 1;
            *(ushort8*)(xbf + (size_t)rb * 32768 +
                        (size_t)(((mt * 32 + sl) * 64 + kh * 32 + n)) * 8) = h;
        }
    } else {
        // ---- cluster part (verbatim logic from verified prep_clusters)
        const int row  = (bid - 4096) * 4 + (t >> 6);   // 0..1023
        const int lane = t & 63;
        const float4* cg = (const float4*)(cl + ((size_t)row << 9) + lane * 8);
        float4 v0 = cg[0], v1 = cg[1];
        float ssq = v0.x*v0.x + v0.y*v0.y + v0.z*v0.z + v0.w*v0.w
                  + v1.x*v1.x + v1.y*v1.y + v1.z*v1.z + v1.w*v1.w;
        ushort8 h;
        h[0]=f2bf(v0.x); h[1]=f2bf(v0.y); h[2]=f2bf(v0.z); h[3]=f2bf(v0.w);
        h[4]=f2bf(v1.x); h[5]=f2bf(v1.y); h[6]=f2bf(v1.z); h[7]=f2bf(v1.w);
        const int n = row & 31, T = row >> 5;
        const int s = lane >> 1, hh = lane & 1;
        *(ushort8*)(cbf + (size_t)((T * 32 + s) * 64 + hh * 32 + n) * 8) = h;
#pragma unroll
        for (int off = 32; off >= 1; off >>= 1) ssq += __shfl_xor(ssq, off);
        if (lane == 0) csq[row] = ssq;
    }
}

// async DMA: one wave stages 4 KB (4 chunks of 64 lanes x 16 B)
__device__ __forceinline__ void stage_a(const unsigned short* __restrict__ src,
                                        unsigned short* dst) {
#pragma unroll
    for (int i = 0; i < 4; ++i)
        __builtin_amdgcn_global_load_lds(
            (const __attribute__((address_space(1))) unsigned int*)(src + i * 512),
            (__attribute__((address_space(3))) unsigned int*)(dst + i * 512),
            16, 0, 0);
}

// Persistent: 256 blocks (1/CU) x 1024 threads; each block does 4x 64-row tiles.
// Double-buffered A in LDS (2x64 KB), staged via global_load_lds overlapped with
// the previous tile's epilogue. B streamed from L2 with depth-2 register ring.
__global__ __launch_bounds__(1024, 4) void soft_assign2(
    const unsigned short* __restrict__ xbf, const unsigned short* __restrict__ cbf,
    const float* __restrict__ csq, const float* __restrict__ xsq,
    float* __restrict__ out) {
    __shared__ unsigned short xs[2][32768];   // 128 KB A double-buffer
    __shared__ float part[64 * 32];           // 8 KB row-sum partials
    __shared__ float xsql[2][64];
    __shared__ float inv[64];

    const int t    = threadIdx.x;
    const int lane = t & 63;
    const int w    = t >> 6;      // wave 0..15
    const int l31  = lane & 31;
    const int half = lane >> 5;

    part[t] = 0.f;
    part[t + 1024] = 0.f;

    const int col0   = w * 64 + l31;
    const float csq0 = csq[col0];
    const float csq1 = csq[col0 + 32];

    // B fragment bases (packed): tiles T0=2w, T1=2w+1; per-step stride 512 ushorts
    const unsigned short* bT0 = cbf + ((size_t)(2 * w) * 2048 + lane) * 8;
    const unsigned short* bT1 = bT0 + 16384;

    // prologue: stage tile 0 into buf 0, load its xsq slice
    stage_a(xbf + (size_t)blockIdx.x * 32768 + (w * 4) * 512 + lane * 8,
            &xs[0][(w * 4) * 512]);
    if (t < 64) xsql[0][t] = xsq[blockIdx.x * 64 + t];
    asm volatile("s_waitcnt vmcnt(0)" ::: "memory");
    __syncthreads();

    int buf = 0;
#pragma unroll 1
    for (int ri = 0; ri < 4; ++ri) {
        const int rb = blockIdx.x + 256 * ri;
        const unsigned short* aB = &xs[buf][0] + lane * 8;

        f32x16 c00, c01, c10, c11;
#pragma unroll
        for (int i = 0; i < 16; ++i) { c00[i]=0.f; c01[i]=0.f; c10[i]=0.f; c11[i]=0.f; }

        // preload B steps 0,1
        bf16x8 b0c = *(const bf16x8*)(bT0);
        bf16x8 b1c = *(const bf16x8*)(bT1);
        bf16x8 b0n = *(const bf16x8*)(bT0 + 512);
        bf16x8 b1n = *(const bf16x8*)(bT1 + 512);

        // ---- K loop: 32 steps, barrier-free, depth-2 B prefetch
#pragma unroll 4
        for (int sl = 0; sl < 32; sl += 2) {
            const int sp2 = (sl + 2) & 31;   // wrap at end: harmless reload
            const int sp3 = (sl + 3) & 31;
            bf16x8 p0 = *(const bf16x8*)(bT0 + sp2 * 512);
            bf16x8 p1 = *(const bf16x8*)(bT1 + sp2 * 512);
            bf16x8 q0 = *(const bf16x8*)(bT0 + sp3 * 512);
            bf16x8 q1 = *(const bf16x8*)(bT1 + sp3 * 512);
            bf16x8 a0 = *(const bf16x8*)(aB + sl * 512);
            bf16x8 a1 = *(const bf16x8*)(aB + 16384 + sl * 512);
            bf16x8 a2 = *(const bf16x8*)(aB + (sl + 1) * 512);
            bf16x8 a3 = *(const bf16x8*)(aB + 16384 + (sl + 1) * 512);
            __builtin_amdgcn_s_setprio(1);
            c00 = __builtin_amdgcn_mfma_f32_32x32x16_bf16(a0, b0c, c00, 0, 0, 0);
            c01 = __builtin_amdgcn_mfma_f32_32x32x16_bf16(a0, b1c, c01, 0, 0, 0);
            c10 = __builtin_amdgcn_mfma_f32_32x32x16_bf16(a1, b0c, c10, 0, 0, 0);
            c11 = __builtin_amdgcn_mfma_f32_32x32x16_bf16(a1, b1c, c11, 0, 0, 0);
            c00 = __builtin_amdgcn_mfma_f32_32x32x16_bf16(a2, b0n, c00, 0, 0, 0);
            c01 = __builtin_amdgcn_mfma_f32_32x32x16_bf16(a2, b1n, c01, 0, 0, 0);
            c10 = __builtin_amdgcn_mfma_f32_32x32x16_bf16(a3, b0n, c10, 0, 0, 0);
            c11 = __builtin_amdgcn_mfma_f32_32x32x16_bf16(a3, b1n, c11, 0, 0, 0);
            __builtin_amdgcn_s_setprio(0);
            b0c = p0; b1c = p1; b0n = q0; b1n = q1;
        }

        // issue next tile's async stage NOW; it completes under the epilogue
        if (ri < 3) {
            stage_a(xbf + (size_t)(rb + 256) * 32768 + (w * 4) * 512 + lane * 8,
                    &xs[buf ^ 1][(w * 4) * 512]);
            if (t < 64) xsql[buf ^ 1][t] = xsq[(rb + 256) * 64 + t];
        }

        // ---- epilogue: q = 1/(1+max(d,0)), accumulate row sums
        // C/D 32x32 layout: col = lane&31, row = (reg&3) + 8*(reg>>2) + 4*(lane>>5)
        const float* xq = xsql[buf];
#pragma unroll
        for (int r = 0; r < 16; ++r) {
            const int rl0 = (r & 3) + 8 * (r >> 2) + 4 * half;
            const float x0 = xq[rl0];
            const float x1 = xq[rl0 + 32];
            float q00 = __builtin_amdgcn_rcpf(1.f + fmaxf(x0 + csq0 - 2.f * c00[r], 0.f));
            float q01 = __builtin_amdgcn_rcpf(1.f + fmaxf(x0 + csq1 - 2.f * c01[r], 0.f));
            float q10 = __builtin_amdgcn_rcpf(1.f + fmaxf(x1 + csq0 - 2.f * c10[r], 0.f));
            float q11 = __builtin_amdgcn_rcpf(1.f + fmaxf(x1 + csq1 - 2.f * c11[r], 0.f));
            c00[r] = q00; c01[r] = q01; c10[r] = q10; c11[r] = q11;
            atomicAdd(&part[rl0 * 32 + l31], q00 + q01);          // 2-way bank: free
            atomicAdd(&part[(rl0 + 32) * 32 + l31], q10 + q11);
        }
        __syncthreads();
        if (t < 64) {
            float s = 0.f;
#pragma unroll
            for (int c2 = 0; c2 < 32; ++c2) {
                const int idx = t * 32 + ((c2 + t) & 31);  // rotated: no bank conflict
                s += part[idx];
                part[idx] = 0.f;                           // re-zero for next tile
            }
            inv[t] = __builtin_amdgcn_rcpf(s);
        }
        // all waves' stage DMA must be complete before anyone reads xs[buf^1]
        asm volatile("s_waitcnt vmcnt(0)" ::: "memory");
        __syncthreads();

        float* og = out + (size_t)rb * 65536;
#pragma unroll
        for (int r = 0; r < 16; ++r) {
            const int rl0 = (r & 3) + 8 * (r >> 2) + 4 * half;
            const float i0 = inv[rl0];
            const float i1 = inv[rl0 + 32];
            og[(size_t)rl0 * 1024 + col0]             = c00[r] * i0;
            og[(size_t)rl0 * 1024 + col0 + 32]        = c01[r] * i0;
            og[(size_t)(rl0 + 32) * 1024 + col0]      = c10[r] * i1;
            og[(size_t)(rl0 + 32) * 1024 + col0 + 32] = c11[r] * i1;
        }
        buf ^= 1;
    }
}

// ===========================================================================
// FALLBACK PATH (verbatim previous verified kernels; used if workspace small)
// ===========================================================================

__global__ __launch_bounds__(256) void prep_clusters(
    const float* __restrict__ cl, unsigned short* __restrict__ cbf,
    float* __restrict__ csq) {
    const int row  = blockIdx.x * 4 + (threadIdx.x >> 6);
    const int lane = threadIdx.x & 63;
    const float4* cg = (const float4*)(cl + ((size_t)row << 9) + lane * 8);
    float4 v0 = cg[0], v1 = cg[1];
    float ssq = v0.x*v0.x + v0.y*v0.y + v0.z*v0.z + v0.w*v0.w
              + v1.x*v1.x + v1.y*v1.y + v1.z*v1.z + v1.w*v1.w;
    ushort8 h;
    h[0]=f2bf(v0.x); h[1]=f2bf(v0.y); h[2]=f2bf(v0.z); h[3]=f2bf(v0.w);
    h[4]=f2bf(v1.x); h[5]=f2bf(v1.y); h[6]=f2bf(v1.z); h[7]=f2bf(v1.w);
    const int n = row & 31, T = row >> 5;
    const int s = lane >> 1, hh = lane & 1;
    *(ushort8*)(cbf + (size_t)((T * 32 + s) * 64 + hh * 32 + n) * 8) = h;
#pragma unroll
    for (int off = 32; off >= 1; off >>= 1) ssq += __shfl_xor(ssq, off);
    if (lane == 0) csq[row] = ssq;
}

__global__ __launch_bounds__(1024, 4) void soft_assign(
    const float* __restrict__ x, const unsigned short* __restrict__ cbf,
    const float* __restrict__ csq, float* __restrict__ out) {
    __shared__ unsigned short xs[2048 * 8];
    __shared__ float part[64 * 32];
    __shared__ float xsq[64];
    __shared__ float inv[64];

    const int t    = threadIdx.x;
    const int lane = t & 63;
    const int w    = t >> 6;
    const int l31  = lane & 31;
    const int half = lane >> 5;
    const int rb   = blockIdx.x;

    part[t] = 0.f;
    part[t + 1024] = 0.f;
    if (t < 64) xsq[t] = 0.f;

    const int col0   = w * 64 + l31;
    const float csq0 = csq[col0];
    const float csq1 = csq[col0 + 32];

    f32x16 c00, c01, c10, c11;
#pragma unroll
    for (int i = 0; i < 16; ++i) { c00[i] = 0.f; c01[i] = 0.f; c10[i] = 0.f; c11[i] = 0.f; }

    const unsigned short* bT0 = cbf + ((size_t)(2 * w) * 32 * 64 + lane) * 8;
    const unsigned short* bT1 = cbf + ((size_t)(2 * w + 1) * 32 * 64 + lane) * 8;
    const unsigned short* aB  = xs + lane * 8;

    bf16x8 b0c = *(const bf16x8*)(bT0);
    bf16x8 b1c = *(const bf16x8*)(bT1);
    bf16x8 b0n = *(const bf16x8*)(bT0 + 512);
    bf16x8 b1n = *(const bf16x8*)(bT1 + 512);

#pragma unroll 1
    for (int ch = 0; ch < 2; ++ch) {
        if (ch) __syncthreads();
#pragma unroll
        for (int i = 0; i < 2; ++i) {
            const int g  = 2 * t + i;
            const int l  = g & 63;
            const int sl = (g >> 6) & 15;
            const int mt = g >> 10;
            const int row = mt * 32 + (l & 31);
            const int d0  = ch * 256 + sl * 16 + (l >> 5) * 8;
            const float4* xg = (const float4*)(x + (size_t)(rb * 64 + row) * 512 + d0);
            float4 v0 = xg[0], v1 = xg[1];
            ushort8 h;
            h[0]=f2bf(v0.x); h[1]=f2bf(v0.y); h[2]=f2bf(v0.z); h[3]=f2bf(v0.w);
            h[4]=f2bf(v1.x); h[5]=f2bf(v1.y); h[6]=f2bf(v1.z); h[7]=f2bf(v1.w);
            *(ushort8*)(xs + (size_t)g * 8) = h;
            float ss = v0.x*v0.x + v0.y*v0.y + v0.z*v0.z + v0.w*v0.w
                     + v1.x*v1.x + v1.y*v1.y + v1.z*v1.z + v1.w*v1.w;
            atomicAdd(&xsq[row], ss);
        }
        __syncthreads();

#pragma unroll 1
        for (int sl = 0; sl < 16; sl += 2) {
            const int sg  = ch * 16 + sl;
            const int sp2 = (sg + 2) & 31;
            const int sp3 = (sg + 3) & 31;
            bf16x8 p0 = *(const bf16x8*)(bT0 + sp2 * 512);
            bf16x8 p1 = *(const bf16x8*)(bT1 + sp2 * 512);
            bf16x8 q0 = *(const bf16x8*)(bT0 + sp3 * 512);
            bf16x8 q1 = *(const bf16x8*)(bT1 + sp3 * 512);
            bf16x8 a0 = *(const bf16x8*)(aB + (sl)     * 512);
            bf16x8 a1 = *(const bf16x8*)(aB + 8192 + (sl)     * 512);
            bf16x8 a2 = *(const bf16x8*)(aB + (sl + 1) * 512);
            bf16x8 a3 = *(const bf16x8*)(aB + 8192 + (sl + 1) * 512);
            c00 = __builtin_amdgcn_mfma_f32_32x32x16_bf16(a0, b0c, c00, 0, 0, 0);
            c01 = __builtin_amdgcn_mfma_f32_32x32x16_bf16(a0, b1c, c01, 0, 0, 0);
            c10 = __builtin_amdgcn_mfma_f32_32x32x16_bf16(a1, b0c, c10, 0, 0, 0);
            c11 = __builtin_amdgcn_mfma_f32_32x32x16_bf16(a1, b1c, c11, 0, 0, 0);
            c00 = __builtin_amdgcn_mfma_f32_32x32x16_bf16(a2, b0n, c00, 0, 0, 0);
            c01 = __builtin_amdgcn_mfma_f32_32x32x16_bf16(a2, b1n, c01, 0, 0, 0);
            c10 = __builtin_amdgcn_mfma_f32_32x32x16_bf16(a3, b0n, c10, 0, 0, 0);
            c11 = __builtin_amdgcn_mfma_f32_32x32x16_bf16(a3, b1n, c11, 0, 0, 0);
            b0c = p0; b1c = p1; b0n = q0; b1n = q1;
        }
    }

#pragma unroll
    for (int r = 0; r < 16; ++r) {
        const int rl0 = (r & 3) + 8 * (r >> 2) + 4 * half;
        const float x0 = xsq[rl0];
        const float x1 = xsq[rl0 + 32];
        float q00 = __builtin_amdgcn_rcpf(1.f + fmaxf(x0 + csq0 - 2.f * c00[r], 0.f));
        float q01 = __builtin_amdgcn_rcpf(1.f + fmaxf(x0 + csq1 - 2.f * c01[r], 0.f));
        float q10 = __builtin_amdgcn_rcpf(1.f + fmaxf(x1 + csq0 - 2.f * c10[r], 0.f));
        float q11 = __builtin_amdgcn_rcpf(1.f + fmaxf(x1 + csq1 - 2.f * c11[r], 0.f));
        c00[r] = q00; c01[r] = q01; c10[r] = q10; c11[r] = q11;
        atomicAdd(&part[rl0 * 32 + l31], q00 + q01);
        atomicAdd(&part[(rl0 + 32) * 32 + l31], q10 + q11);
    }
    __syncthreads();
    if (t < 64) {
        float s = 0.f;
#pragma unroll
        for (int c = 0; c < 32; ++c) s += part[t * 32 + ((c + t) & 31)];
        inv[t] = __builtin_amdgcn_rcpf(s);
    }
    __syncthreads();

    float* og = out + (size_t)rb * 64 * 1024;
#pragma unroll
    for (int r = 0; r < 16; ++r) {
        const int rl0 = (r & 3) + 8 * (r >> 2) + 4 * half;
        const float i0 = inv[rl0];
        const float i1 = inv[rl0 + 32];
        og[(size_t)rl0 * 1024 + col0]             = c00[r] * i0;
        og[(size_t)rl0 * 1024 + col0 + 32]        = c01[r] * i0;
        og[(size_t)(rl0 + 32) * 1024 + col0]      = c10[r] * i1;
        og[(size_t)(rl0 + 32) * 1024 + col0 + 32] = c11[r] * i1;
    }
}

extern "C" void kernel_launch(void* const* d_in, const int* in_sizes, int n_in,
                              void* d_out, int out_size, void* d_ws, size_t ws_size,
                              hipStream_t stream) {
    const float* x  = (const float*)d_in[0];   // (65536, 512) fp32
    const float* cl = (const float*)d_in[1];   // (1024, 512) fp32
    float* out = (float*)d_out;                // (65536, 1024) fp32

    // new-path workspace layout
    const size_t CBF_OFF = 0;                  // 1,048,576 B
    const size_t CSQ_OFF = 1048576;            //     4,096 B
    const size_t XSQ_OFF = 1052672;            //   262,144 B
    const size_t XBF_OFF = 1314816;            // 67,108,864 B
    const size_t NEED    = 68423680;

    if (ws_size >= NEED) {
        unsigned short* cbf = (unsigned short*)((char*)d_ws + CBF_OFF);
        float*          csq = (float*)((char*)d_ws + CSQ_OFF);
        float*          xsq = (float*)((char*)d_ws + XSQ_OFF);
        unsigned short* xbf = (unsigned short*)((char*)d_ws + XBF_OFF);
        prep_all<<<4352, 256, 0, stream>>>(x, cl, xbf, cbf, csq, xsq);
        soft_assign2<<<256, 1024, 0, stream>>>(xbf, cbf, csq, xsq, out);
    } else {
        unsigned short* cbf = (unsigned short*)d_ws;
        float* csq = (float*)((char*)d_ws + (size_t)1024 * 512 * 2);
        prep_clusters<<<256, 256, 0, stream>>>(cl, cbf, csq);
        soft_assign<<<1024, 1024, 0, stream>>>(x, cbf, csq, out);
    }
}

// Round 2
// 637.353 us; speedup vs baseline: 1.0262x; 1.0262x over previous
//
#include <hip/hip_runtime.h>

typedef __bf16 bf16x8 __attribute__((ext_vector_type(8)));
typedef float f32x16 __attribute__((ext_vector_type(16)));
typedef unsigned short ushort8 __attribute__((ext_vector_type(8)));

__device__ __forceinline__ unsigned short f2bf(float f) {
    unsigned int u = __float_as_uint(f);
    u += 0x7FFFu + ((u >> 16) & 1u);   // round-to-nearest-even
    return (unsigned short)(u >> 16);
}

// ===========================================================================
// NEW PATH (needs ~68.4 MB workspace)
// ws layout: [cbf 1 MB][csq 4 KB][xsq 256 KB][xbf 64 MB]
// xbf fragment layout per 64-row block rb:
//   xbf[rb*32768 + ((mt*32 + sl)*64 + kh*32 + n)*8 + j] = x[rb*64+mt*32+n][sl*16+kh*8+j]
// so a wave's A-fragment (mt, sl) is 64 lanes x 16 B contiguous -> global_load_lds-able.
// cbf layout identical to previous session (verified):
//   cbf[((T*32 + s)*64 + kh*32 + n)*8 + j] = cl[T*32+n][s*16+kh*8+j]
// ===========================================================================

__global__ __launch_bounds__(256) void prep_all(
    const float* __restrict__ x, const float* __restrict__ cl,
    unsigned short* __restrict__ xbf, unsigned short* __restrict__ cbf,
    float* __restrict__ csq, float* __restrict__ xsq) {
    const int bid = blockIdx.x;
    const int t   = threadIdx.x;
    if (bid < 4096) {
        // ---- x part: 1M threads, thread -> (row = gx>>4, 32-col chunk c = gx&15)
        const int gx  = bid * 256 + t;
        const int row = gx >> 4, c = gx & 15;
        const float4* xg = (const float4*)(x + ((size_t)row << 9) + c * 32);
        float4 v[8];
#pragma unroll
        for (int i = 0; i < 8; ++i) v[i] = xg[i];
        float ssq = 0.f;
#pragma unroll
        for (int i = 0; i < 8; ++i)
            ssq += v[i].x*v[i].x + v[i].y*v[i].y + v[i].z*v[i].z + v[i].w*v[i].w;
        // reduce ||x||^2 across the 16 lanes sharing a row (lane bits 0..3)
#pragma unroll
        for (int off = 1; off <= 8; off <<= 1) ssq += __shfl_xor(ssq, off);
        if ((t & 15) == 0) xsq[row] = ssq;

        const int rb = row >> 6, mt = (row >> 5) & 1, n = row & 31;
#pragma unroll
        for (int g = 0; g < 4; ++g) {
            const float4 a = v[2*g], b = v[2*g+1];
            ushort8 h;
            h[0]=f2bf(a.x); h[1]=f2bf(a.y); h[2]=f2bf(a.z); h[3]=f2bf(a.w);
            h[4]=f2bf(b.x); h[5]=f2bf(b.y); h[6]=f2bf(b.z); h[7]=f2bf(b.w);
            const int d0 = c * 32 + g * 8;
            const int sl = d0 >> 4, kh = (d0 >> 3) & 1;
            *(ushort8*)(xbf + (size_t)rb * 32768 +
                        (size_t)(((mt * 32 + sl) * 64 + kh * 32 + n)) * 8) = h;
        }
    } else {
        // ---- cluster part (verbatim logic from verified prep_clusters)
        const int row  = (bid - 4096) * 4 + (t >> 6);   // 0..1023
        const int lane = t & 63;
        const float4* cg = (const float4*)(cl + ((size_t)row << 9) + lane * 8);
        float4 v0 = cg[0], v1 = cg[1];
        float ssq = v0.x*v0.x + v0.y*v0.y + v0.z*v0.z + v0.w*v0.w
                  + v1.x*v1.x + v1.y*v1.y + v1.z*v1.z + v1.w*v1.w;
        ushort8 h;
        h[0]=f2bf(v0.x); h[1]=f2bf(v0.y); h[2]=f2bf(v0.z); h[3]=f2bf(v0.w);
        h[4]=f2bf(v1.x); h[5]=f2bf(v1.y); h[6]=f2bf(v1.z); h[7]=f2bf(v1.w);
        const int n = row & 31, T = row >> 5;
        const int s = lane >> 1, hh = lane & 1;
        *(ushort8*)(cbf + (size_t)((T * 32 + s) * 64 + hh * 32 + n) * 8) = h;
#pragma unroll
        for (int off = 32; off >= 1; off >>= 1) ssq += __shfl_xor(ssq, off);
        if (lane == 0) csq[row] = ssq;
    }
}

// async DMA: one wave stages 4 KB (4 chunks of 64 lanes x 16 B)
__device__ __forceinline__ void stage_a(const unsigned short* __restrict__ src,
                                        unsigned short* dst) {
#pragma unroll
    for (int i = 0; i < 4; ++i)
        __builtin_amdgcn_global_load_lds(
            (const __attribute__((address_space(1))) unsigned int*)(src + i * 512),
            (__attribute__((address_space(3))) unsigned int*)(dst + i * 512),
            16, 0, 0);
}

// Persistent: 256 blocks (1/CU) x 1024 threads; each block does 4x 64-row tiles.
// Double-buffered A in LDS (2x64 KB), staged via global_load_lds overlapped with
// the previous tile's epilogue. B streamed from L2 with depth-2 register ring.
__global__ __launch_bounds__(1024, 4) void soft_assign2(
    const unsigned short* __restrict__ xbf, const unsigned short* __restrict__ cbf,
    const float* __restrict__ csq, const float* __restrict__ xsq,
    float* __restrict__ out) {
    __shared__ unsigned short xs[2][32768];   // 128 KB A double-buffer
    __shared__ float part[64 * 32];           // 8 KB row-sum partials
    __shared__ float xsql[2][64];
    __shared__ float inv[64];

    const int t    = threadIdx.x;
    const int lane = t & 63;
    const int w    = t >> 6;      // wave 0..15
    const int l31  = lane & 31;
    const int half = lane >> 5;

    part[t] = 0.f;
    part[t + 1024] = 0.f;

    const int col0   = w * 64 + l31;
    const float csq0 = csq[col0];
    const float csq1 = csq[col0 + 32];

    // B fragment bases (packed): tiles T0=2w, T1=2w+1; per-step stride 512 ushorts
    const unsigned short* bT0 = cbf + ((size_t)(2 * w) * 2048 + lane) * 8;
    const unsigned short* bT1 = bT0 + 16384;

    // prologue: stage tile 0 into buf 0, load its xsq slice
    stage_a(xbf + (size_t)blockIdx.x * 32768 + (w * 4) * 512 + lane * 8,
            &xs[0][(w * 4) * 512]);
    if (t < 64) xsql[0][t] = xsq[blockIdx.x * 64 + t];
    asm volatile("s_waitcnt vmcnt(0)" ::: "memory");
    __syncthreads();

    int buf = 0;
#pragma unroll 1
    for (int ri = 0; ri < 4; ++ri) {
        const int rb = blockIdx.x + 256 * ri;
        const unsigned short* aB = &xs[buf][0] + lane * 8;

        f32x16 c00, c01, c10, c11;
#pragma unroll
        for (int i = 0; i < 16; ++i) { c00[i]=0.f; c01[i]=0.f; c10[i]=0.f; c11[i]=0.f; }

        // preload B steps 0,1
        bf16x8 b0c = *(const bf16x8*)(bT0);
        bf16x8 b1c = *(const bf16x8*)(bT1);
        bf16x8 b0n = *(const bf16x8*)(bT0 + 512);
        bf16x8 b1n = *(const bf16x8*)(bT1 + 512);

        // ---- K loop: 32 steps, barrier-free, depth-2 B prefetch
#pragma unroll 4
        for (int sl = 0; sl < 32; sl += 2) {
            const int sp2 = (sl + 2) & 31;   // wrap at end: harmless reload
            const int sp3 = (sl + 3) & 31;
            bf16x8 p0 = *(const bf16x8*)(bT0 + sp2 * 512);
            bf16x8 p1 = *(const bf16x8*)(bT1 + sp2 * 512);
            bf16x8 q0 = *(const bf16x8*)(bT0 + sp3 * 512);
            bf16x8 q1 = *(const bf16x8*)(bT1 + sp3 * 512);
            bf16x8 a0 = *(const bf16x8*)(aB + sl * 512);
            bf16x8 a1 = *(const bf16x8*)(aB + 16384 + sl * 512);
            bf16x8 a2 = *(const bf16x8*)(aB + (sl + 1) * 512);
            bf16x8 a3 = *(const bf16x8*)(aB + 16384 + (sl + 1) * 512);
            __builtin_amdgcn_s_setprio(1);
            c00 = __builtin_amdgcn_mfma_f32_32x32x16_bf16(a0, b0c, c00, 0, 0, 0);
            c01 = __builtin_amdgcn_mfma_f32_32x32x16_bf16(a0, b1c, c01, 0, 0, 0);
            c10 = __builtin_amdgcn_mfma_f32_32x32x16_bf16(a1, b0c, c10, 0, 0, 0);
            c11 = __builtin_amdgcn_mfma_f32_32x32x16_bf16(a1, b1c, c11, 0, 0, 0);
            c00 = __builtin_amdgcn_mfma_f32_32x32x16_bf16(a2, b0n, c00, 0, 0, 0);
            c01 = __builtin_amdgcn_mfma_f32_32x32x16_bf16(a2, b1n, c01, 0, 0, 0);
            c10 = __builtin_amdgcn_mfma_f32_32x32x16_bf16(a3, b0n, c10, 0, 0, 0);
            c11 = __builtin_amdgcn_mfma_f32_32x32x16_bf16(a3, b1n, c11, 0, 0, 0);
            __builtin_amdgcn_s_setprio(0);
            b0c = p0; b1c = p1; b0n = q0; b1n = q1;
        }

        // issue next tile's async stage NOW; it completes under the epilogue
        if (ri < 3) {
            stage_a(xbf + (size_t)(rb + 256) * 32768 + (w * 4) * 512 + lane * 8,
                    &xs[buf ^ 1][(w * 4) * 512]);
            if (t < 64) xsql[buf ^ 1][t] = xsq[(rb + 256) * 64 + t];
        }

        // ---- epilogue: q = 1/(1+max(d,0)), accumulate row sums
        // C/D 32x32 layout: col = lane&31, row = (reg&3) + 8*(reg>>2) + 4*(lane>>5)
        const float* xq = xsql[buf];
#pragma unroll
        for (int r = 0; r < 16; ++r) {
            const int rl0 = (r & 3) + 8 * (r >> 2) + 4 * half;
            const float x0 = xq[rl0];
            const float x1 = xq[rl0 + 32];
            float q00 = __builtin_amdgcn_rcpf(1.f + fmaxf(x0 + csq0 - 2.f * c00[r], 0.f));
            float q01 = __builtin_amdgcn_rcpf(1.f + fmaxf(x0 + csq1 - 2.f * c01[r], 0.f));
            float q10 = __builtin_amdgcn_rcpf(1.f + fmaxf(x1 + csq0 - 2.f * c10[r], 0.f));
            float q11 = __builtin_amdgcn_rcpf(1.f + fmaxf(x1 + csq1 - 2.f * c11[r], 0.f));
            c00[r] = q00; c01[r] = q01; c10[r] = q10; c11[r] = q11;
            atomicAdd(&part[rl0 * 32 + l31], q00 + q01);          // 2-way bank: free
            atomicAdd(&part[(rl0 + 32) * 32 + l31], q10 + q11);
        }
        __syncthreads();
        if (t < 64) {
            float s = 0.f;
#pragma unroll
            for (int c2 = 0; c2 < 32; ++c2) {
                const int idx = t * 32 + ((c2 + t) & 31);  // rotated: no bank conflict
                s += part[idx];
                part[idx] = 0.f;                           // re-zero for next tile
            }
            inv[t] = __builtin_amdgcn_rcpf(s);
        }
        // all waves' stage DMA must be complete before anyone reads xs[buf^1]
        asm volatile("s_waitcnt vmcnt(0)" ::: "memory");
        __syncthreads();

        float* og = out + (size_t)rb * 65536;
#pragma unroll
        for (int r = 0; r < 16; ++r) {
            const int rl0 = (r & 3) + 8 * (r >> 2) + 4 * half;
            const float i0 = inv[rl0];
            const float i1 = inv[rl0 + 32];
            og[(size_t)rl0 * 1024 + col0]             = c00[r] * i0;
            og[(size_t)rl0 * 1024 + col0 + 32]        = c01[r] * i0;
            og[(size_t)(rl0 + 32) * 1024 + col0]      = c10[r] * i1;
            og[(size_t)(rl0 + 32) * 1024 + col0 + 32] = c11[r] * i1;
        }
        buf ^= 1;
    }
}

// ===========================================================================
// FALLBACK PATH (verbatim previous verified kernels; used if workspace small)
// ===========================================================================

__global__ __launch_bounds__(256) void prep_clusters(
    const float* __restrict__ cl, unsigned short* __restrict__ cbf,
    float* __restrict__ csq) {
    const int row  = blockIdx.x * 4 + (threadIdx.x >> 6);
    const int lane = threadIdx.x & 63;
    const float4* cg = (const float4*)(cl + ((size_t)row << 9) + lane * 8);
    float4 v0 = cg[0], v1 = cg[1];
    float ssq = v0.x*v0.x + v0.y*v0.y + v0.z*v0.z + v0.w*v0.w
              + v1.x*v1.x + v1.y*v1.y + v1.z*v1.z + v1.w*v1.w;
    ushort8 h;
    h[0]=f2bf(v0.x); h[1]=f2bf(v0.y); h[2]=f2bf(v0.z); h[3]=f2bf(v0.w);
    h[4]=f2bf(v1.x); h[5]=f2bf(v1.y); h[6]=f2bf(v1.z); h[7]=f2bf(v1.w);
    const int n = row & 31, T = row >> 5;
    const int s = lane >> 1, hh = lane & 1;
    *(ushort8*)(cbf + (size_t)((T * 32 + s) * 64 + hh * 32 + n) * 8) = h;
#pragma unroll
    for (int off = 32; off >= 1; off >>= 1) ssq += __shfl_xor(ssq, off);
    if (lane == 0) csq[row] = ssq;
}

__global__ __launch_bounds__(1024, 4) void soft_assign(
    const float* __restrict__ x, const unsigned short* __restrict__ cbf,
    const float* __restrict__ csq, float* __restrict__ out) {
    __shared__ unsigned short xs[2048 * 8];
    __shared__ float part[64 * 32];
    __shared__ float xsq[64];
    __shared__ float inv[64];

    const int t    = threadIdx.x;
    const int lane = t & 63;
    const int w    = t >> 6;
    const int l31  = lane & 31;
    const int half = lane >> 5;
    const int rb   = blockIdx.x;

    part[t] = 0.f;
    part[t + 1024] = 0.f;
    if (t < 64) xsq[t] = 0.f;

    const int col0   = w * 64 + l31;
    const float csq0 = csq[col0];
    const float csq1 = csq[col0 + 32];

    f32x16 c00, c01, c10, c11;
#pragma unroll
    for (int i = 0; i < 16; ++i) { c00[i] = 0.f; c01[i] = 0.f; c10[i] = 0.f; c11[i] = 0.f; }

    const unsigned short* bT0 = cbf + ((size_t)(2 * w) * 32 * 64 + lane) * 8;
    const unsigned short* bT1 = cbf + ((size_t)(2 * w + 1) * 32 * 64 + lane) * 8;
    const unsigned short* aB  = xs + lane * 8;

    bf16x8 b0c = *(const bf16x8*)(bT0);
    bf16x8 b1c = *(const bf16x8*)(bT1);
    bf16x8 b0n = *(const bf16x8*)(bT0 + 512);
    bf16x8 b1n = *(const bf16x8*)(bT1 + 512);

#pragma unroll 1
    for (int ch = 0; ch < 2; ++ch) {
        if (ch) __syncthreads();
#pragma unroll
        for (int i = 0; i < 2; ++i) {
            const int g  = 2 * t + i;
            const int l  = g & 63;
            const int sl = (g >> 6) & 15;
            const int mt = g >> 10;
            const int row = mt * 32 + (l & 31);
            const int d0  = ch * 256 + sl * 16 + (l >> 5) * 8;
            const float4* xg = (const float4*)(x + (size_t)(rb * 64 + row) * 512 + d0);
            float4 v0 = xg[0], v1 = xg[1];
            ushort8 h;
            h[0]=f2bf(v0.x); h[1]=f2bf(v0.y); h[2]=f2bf(v0.z); h[3]=f2bf(v0.w);
            h[4]=f2bf(v1.x); h[5]=f2bf(v1.y); h[6]=f2bf(v1.z); h[7]=f2bf(v1.w);
            *(ushort8*)(xs + (size_t)g * 8) = h;
            float ss = v0.x*v0.x + v0.y*v0.y + v0.z*v0.z + v0.w*v0.w
                     + v1.x*v1.x + v1.y*v1.y + v1.z*v1.z + v1.w*v1.w;
            atomicAdd(&xsq[row], ss);
        }
        __syncthreads();

#pragma unroll 1
        for (int sl = 0; sl < 16; sl += 2) {
            const int sg  = ch * 16 + sl;
            const int sp2 = (sg + 2) & 31;
            const int sp3 = (sg + 3) & 31;
            bf16x8 p0 = *(const bf16x8*)(bT0 + sp2 * 512);
            bf16x8 p1 = *(const bf16x8*)(bT1 + sp2 * 512);
            bf16x8 q0 = *(const bf16x8*)(bT0 + sp3 * 512);
            bf16x8 q1 = *(const bf16x8*)(bT1 + sp3 * 512);
            bf16x8 a0 = *(const bf16x8*)(aB + (sl)     * 512);
            bf16x8 a1 = *(const bf16x8*)(aB + 8192 + (sl)     * 512);
            bf16x8 a2 = *(const bf16x8*)(aB + (sl + 1) * 512);
            bf16x8 a3 = *(const bf16x8*)(aB + 8192 + (sl + 1) * 512);
            c00 = __builtin_amdgcn_mfma_f32_32x32x16_bf16(a0, b0c, c00, 0, 0, 0);
            c01 = __builtin_amdgcn_mfma_f32_32x32x16_bf16(a0, b1c, c01, 0, 0, 0);
            c10 = __builtin_amdgcn_mfma_f32_32x32x16_bf16(a1, b0c, c10, 0, 0, 0);
            c11 = __builtin_amdgcn_mfma_f32_32x32x16_bf16(a1, b1c, c11, 0, 0, 0);
            c00 = __builtin_amdgcn_mfma_f32_32x32x16_bf16(a2, b0n, c00, 0, 0, 0);
            c01 = __builtin_amdgcn_mfma_f32_32x32x16_bf16(a2, b1n, c01, 0, 0, 0);
            c10 = __builtin_amdgcn_mfma_f32_32x32x16_bf16(a3, b0n, c10, 0, 0, 0);
            c11 = __builtin_amdgcn_mfma_f32_32x32x16_bf16(a3, b1n, c11, 0, 0, 0);
            b0c = p0; b1c = p1; b0n = q0; b1n = q1;
        }
    }

#pragma unroll
    for (int r = 0; r < 16; ++r) {
        const int rl0 = (r & 3) + 8 * (r >> 2) + 4 * half;
        const float x0 = xsq[rl0];
        const float x1 = xsq[rl0 + 32];
        float q00 = __builtin_amdgcn_rcpf(1.f + fmaxf(x0 + csq0 - 2.f * c00[r], 0.f));
        float q01 = __builtin_amdgcn_rcpf(1.f + fmaxf(x0 + csq1 - 2.f * c01[r], 0.f));
        float q10 = __builtin_amdgcn_rcpf(1.f + fmaxf(x1 + csq0 - 2.f * c10[r], 0.f));
        float q11 = __builtin_amdgcn_rcpf(1.f + fmaxf(x1 + csq1 - 2.f * c11[r], 0.f));
        c00[r] = q00; c01[r] = q01; c10[r] = q10; c11[r] = q11;
        atomicAdd(&part[rl0 * 32 + l31], q00 + q01);
        atomicAdd(&part[(rl0 + 32) * 32 + l31], q10 + q11);
    }
    __syncthreads();
    if (t < 64) {
        float s = 0.f;
#pragma unroll
        for (int c = 0; c < 32; ++c) s += part[t * 32 + ((c + t) & 31)];
        inv[t] = __builtin_amdgcn_rcpf(s);
    }
    __syncthreads();

    float* og = out + (size_t)rb * 64 * 1024;
#pragma unroll
    for (int r = 0; r < 16; ++r) {
        const int rl0 = (r & 3) + 8 * (r >> 2) + 4 * half;
        const float i0 = inv[rl0];
        const float i1 = inv[rl0 + 32];
        og[(size_t)rl0 * 1024 + col0]             = c00[r] * i0;
        og[(size_t)rl0 * 1024 + col0 + 32]        = c01[r] * i0;
        og[(size_t)(rl0 + 32) * 1024 + col0]      = c10[r] * i1;
        og[(size_t)(rl0 + 32) * 1024 + col0 + 32] = c11[r] * i1;
    }
}

extern "C" void kernel_launch(void* const* d_in, const int* in_sizes, int n_in,
                              void* d_out, int out_size, void* d_ws, size_t ws_size,
                              hipStream_t stream) {
    const float* x  = (const float*)d_in[0];   // (65536, 512) fp32
    const float* cl = (const float*)d_in[1];   // (1024, 512) fp32
    float* out = (float*)d_out;                // (65536, 1024) fp32

    // new-path workspace layout
    const size_t CBF_OFF = 0;                  // 1,048,576 B
    const size_t CSQ_OFF = 1048576;            //     4,096 B
    const size_t XSQ_OFF = 1052672;            //   262,144 B
    const size_t XBF_OFF = 1314816;            // 67,108,864 B
    const size_t NEED    = 68423680;

    if (ws_size >= NEED) {
        unsigned short* cbf = (unsigned short*)((char*)d_ws + CBF_OFF);
        float*          csq = (float*)((char*)d_ws + CSQ_OFF);
        float*          xsq = (float*)((char*)d_ws + XSQ_OFF);
        unsigned short* xbf = (unsigned short*)((char*)d_ws + XBF_OFF);
        prep_all<<<4352, 256, 0, stream>>>(x, cl, xbf, cbf, csq, xsq);
        soft_assign2<<<256, 1024, 0, stream>>>(xbf, cbf, csq, xsq, out);
    } else {
        unsigned short* cbf = (unsigned short*)d_ws;
        float* csq = (float*)((char*)d_ws + (size_t)1024 * 512 * 2);
        prep_clusters<<<256, 256, 0, stream>>>(cl, cbf, csq);
        soft_assign<<<1024, 1024, 0, stream>>>(x, cbf, csq, out);
    }
}